// Round 8
// baseline (737.946 us; speedup 1.0000x reference)
//
#include <hip/hip_runtime.h>
#include <cstddef>

#define BD 128
#define NS 8
#define ROWS 8
#define BLOCK 256

typedef float __attribute__((ext_vector_type(2))) f32x2;

__device__ __forceinline__ float sigm(float x) { return 1.0f / (1.0f + __expf(-x)); }

__device__ __forceinline__ void nt_store2(float2 v, float2* p) {
    f32x2 t; t.x = v.x; t.y = v.y;
    __builtin_nontemporal_store(t, (f32x2*)p);
}

// ROWS=8, LDS 17.4KB, VGPR<=64: launch_bounds(256,8) -> 8 waves/SIMD (32/CU).
// Round-2 measured this structure at 290us with bounds(256,4) (occ 50%);
// this round changes ONLY the occupancy cap (latency-bound theory).
__global__ __launch_bounds__(BLOCK, 8)
void sbcore_kernel(
    const float* __restrict__ g_signal, const float* __restrict__ g_prev,
    const float* __restrict__ g_hidden, const float* __restrict__ g_keys,
    const float* __restrict__ g_vals, const float* __restrict__ g_str,
    const float* __restrict__ g_age,
    const float* __restrict__ w_rq, const float* __restrict__ w_mix,
    const float* __restrict__ b_mix, const float* __restrict__ w_key,
    const float* __restrict__ b_key, const float* __restrict__ w_val,
    const float* __restrict__ b_val, const float* __restrict__ w_wr,
    const float* __restrict__ b_wr, const float* __restrict__ w_pe,
    const float* __restrict__ b_pe, const float* __restrict__ w_mg,
    const float* __restrict__ b_mg,
    float* __restrict__ o_read, float* __restrict__ o_keys,
    float* __restrict__ o_vals, float* __restrict__ o_str,
    float* __restrict__ o_age)
{
    // sig/prv/hid are REUSED after the matvec barrier to hold q / cand_key / cand_value.
    __shared__ __align__(16) float sig_s[ROWS][BD];
    __shared__ __align__(16) float prv_s[ROWS][BD];
    __shared__ __align__(16) float hid_s[ROWS][BD];
    __shared__ __align__(16) float wmix_s[2*BD], wwr_s[2*BD], wpe_s[2*BD], wmg_s[2*BD];
    __shared__ __align__(16) float str_s[ROWS*NS], age_s[ROWS*NS];
    __shared__ float red_s[4][4][2];
    __shared__ float ckinv_s[ROWS];
    __shared__ __align__(16) float head_s[ROWS][4];   // pmix, pwr, ppe, pmg per row

    const int tid = threadIdx.x;
    const int row0 = blockIdx.x * ROWS;

    // ---- phase 0: cooperative staging ----
    for (int i = tid; i < ROWS*BD; i += BLOCK) {
        int r = i >> 7, dd = i & (BD-1);
        size_t g = (size_t)(row0 + r) * BD + dd;
        sig_s[r][dd] = g_signal[g];
        prv_s[r][dd] = g_prev[g];
        hid_s[r][dd] = g_hidden[g];
    }
    if (tid < ROWS*NS) {
        str_s[tid] = g_str[(size_t)row0*NS + tid];
        age_s[tid] = g_age[(size_t)row0*NS + tid];
    }
    wmix_s[tid] = w_mix[tid];
    wwr_s[tid]  = w_wr[tid];
    wpe_s[tid]  = w_pe[tid];
    wmg_s[tid]  = w_mg[tid];
    __syncthreads();

    // ---- phase 0.5: scalar heads (mix/write/persist/merge), hoisted out of the
    //      per-row serial path. 32 dots (8 rows x 4 heads), 8 threads each. ----
    {
        const int dotid = tid >> 3;      // 0..31
        const int hr    = dotid >> 2;    // row 0..7
        const int hh    = dotid & 3;     // head 0..3
        const int hj    = tid & 7;       // 32-dim chunk
        const float* ws = (hh==0) ? wmix_s : (hh==1) ? wwr_s : (hh==2) ? wpe_s : wmg_s;
        const float* xb;
        if (hj < 4) xb = &sig_s[hr][0];
        else        xb = ((hh==0) ? &prv_s[hr][0] : &hid_s[hr][0]) - BD;
        float p = 0.f;
#pragma unroll
        for (int q = 0; q < 8; ++q) {
            const int k = hj*32 + q*4;
            const float4 w4 = *(const float4*)&ws[k];
            const float4 x4 = *(const float4*)&xb[k];
            p = fmaf(x4.w, w4.w, fmaf(x4.z, w4.z, fmaf(x4.y, w4.y, fmaf(x4.x, w4.x, p))));
        }
        p += __shfl_xor(p, 1); p += __shfl_xor(p, 2); p += __shfl_xor(p, 4);
        if (hj == 0) head_s[hr][hh] = p;
    }

    // ---- phase 1: fused matvecs (query / cand_key / cand_value) ----
    const int d    = tid & (BD-1);   // output dim
    const int h    = tid >> 7;       // row half (0: rows 0-3, 1: rows 4-7)
    const int wave = tid >> 6;
    const int lane = tid & 63;

    float aq[4], ak[4], av[4];
#pragma unroll
    for (int r = 0; r < 4; ++r) { aq[r] = 0.f; ak[r] = 0.f; av[r] = 0.f; }

    // k in [0,128): signal feeds all three heads
    for (int kk = 0; kk < BD; kk += 4) {
        float wq0 = w_rq[(kk+0)*BD + d], wq1 = w_rq[(kk+1)*BD + d],
              wq2 = w_rq[(kk+2)*BD + d], wq3 = w_rq[(kk+3)*BD + d];
        float wk0 = w_key[(kk+0)*BD + d], wk1 = w_key[(kk+1)*BD + d],
              wk2 = w_key[(kk+2)*BD + d], wk3 = w_key[(kk+3)*BD + d];
        float wv0 = w_val[(kk+0)*BD + d], wv1 = w_val[(kk+1)*BD + d],
              wv2 = w_val[(kk+2)*BD + d], wv3 = w_val[(kk+3)*BD + d];
#pragma unroll
        for (int r = 0; r < 4; ++r) {
            const float4 s4 = *(const float4*)&sig_s[h*4 + r][kk];
            aq[r] = fmaf(s4.w, wq3, fmaf(s4.z, wq2, fmaf(s4.y, wq1, fmaf(s4.x, wq0, aq[r]))));
            ak[r] = fmaf(s4.w, wk3, fmaf(s4.z, wk2, fmaf(s4.y, wk1, fmaf(s4.x, wk0, ak[r]))));
            av[r] = fmaf(s4.w, wv3, fmaf(s4.z, wv2, fmaf(s4.y, wv1, fmaf(s4.x, wv0, av[r]))));
        }
    }
    // k in [128,256): previous feeds query; hidden feeds key/value
    for (int kk = 0; kk < BD; kk += 4) {
        const int k = kk + BD;
        float wq0 = w_rq[(k+0)*BD + d], wq1 = w_rq[(k+1)*BD + d],
              wq2 = w_rq[(k+2)*BD + d], wq3 = w_rq[(k+3)*BD + d];
        float wk0 = w_key[(k+0)*BD + d], wk1 = w_key[(k+1)*BD + d],
              wk2 = w_key[(k+2)*BD + d], wk3 = w_key[(k+3)*BD + d];
        float wv0 = w_val[(k+0)*BD + d], wv1 = w_val[(k+1)*BD + d],
              wv2 = w_val[(k+2)*BD + d], wv3 = w_val[(k+3)*BD + d];
#pragma unroll
        for (int r = 0; r < 4; ++r) {
            const float4 p4 = *(const float4*)&prv_s[h*4 + r][kk];
            const float4 h4 = *(const float4*)&hid_s[h*4 + r][kk];
            aq[r] = fmaf(p4.w, wq3, fmaf(p4.z, wq2, fmaf(p4.y, wq1, fmaf(p4.x, wq0, aq[r]))));
            ak[r] = fmaf(h4.w, wk3, fmaf(h4.z, wk2, fmaf(h4.y, wk1, fmaf(h4.x, wk0, ak[r]))));
            av[r] = fmaf(h4.w, wv3, fmaf(h4.z, wv2, fmaf(h4.y, wv1, fmaf(h4.x, wv0, av[r]))));
        }
    }

    const float bk = b_key[d], bv = b_val[d];
    float ckr[4], cvr[4], q2[4], c2[4];
#pragma unroll
    for (int r = 0; r < 4; ++r) {
        ckr[r] = tanhf(ak[r] + bk);
        cvr[r] = tanhf(av[r] + bv);
        q2[r]  = aq[r] * aq[r];
        c2[r]  = ckr[r] * ckr[r];
    }
#pragma unroll
    for (int off = 32; off > 0; off >>= 1) {
#pragma unroll
        for (int r = 0; r < 4; ++r) {
            q2[r] += __shfl_xor(q2[r], off);
            c2[r] += __shfl_xor(c2[r], off);
        }
    }
    if (lane == 0) {
#pragma unroll
        for (int r = 0; r < 4; ++r) { red_s[wave][r][0] = q2[r]; red_s[wave][r][1] = c2[r]; }
    }
    __syncthreads();
#pragma unroll
    for (int r = 0; r < 4; ++r) {
        float sq = red_s[h*2][r][0] + red_s[h*2+1][r][0];
        float sc = red_s[h*2][r][1] + red_s[h*2+1][r][1];
        float qi = 1.0f / fmaxf(sqrtf(sq), 1e-6f);
        // overwrite staging arrays (all reads of them completed before prior barrier)
        sig_s[h*4 + r][d] = aq[r] * qi;     // normalized query
        prv_s[h*4 + r][d] = ckr[r];         // raw candidate key
        hid_s[h*4 + r][d] = cvr[r];         // raw candidate value
        if (d == 0) ckinv_s[h*4 + r] = 1.0f / fmaxf(sqrtf(sc), 1e-6f);
    }
    __syncthreads();

    // ---- phase 2: one wave per 2 rows, slot logic ----
    const float bmix = b_mix[0], bwr = b_wr[0], bpe = b_pe[0], bmg = b_mg[0];
    const int sj = lane & 7;                 // 16-dim chunk within slot group

    for (int rr = 0; rr < 2; ++rr) {
        const int r = wave*2 + rr;
        const size_t row = (size_t)row0 + r;
        const size_t kvb = row * (size_t)(NS*BD);

        // --- slot dot-products: lane = slot*8 + chunk; 16 dims per lane ---
        const float4* kp4  = (const float4*)(g_keys + kvb);
        const float4* qrow = (const float4*)&sig_s[r][0];
        const float4* crow = (const float4*)&prv_s[r][0];
        float pk = 0.f, pq = 0.f, pc = 0.f;
#pragma unroll
        for (int q = 0; q < 4; ++q) {
            const float4 k4 = kp4[4*lane + q];       // coalesced: float4 idx = 4*lane+q
            const float4 q4 = qrow[sj*4 + q];
            const float4 c4 = crow[sj*4 + q];
            pk = fmaf(k4.w,k4.w, fmaf(k4.z,k4.z, fmaf(k4.y,k4.y, fmaf(k4.x,k4.x, pk))));
            pq = fmaf(q4.w,k4.w, fmaf(q4.z,k4.z, fmaf(q4.y,k4.y, fmaf(q4.x,k4.x, pq))));
            pc = fmaf(c4.w,k4.w, fmaf(c4.z,k4.z, fmaf(c4.y,k4.y, fmaf(c4.x,k4.x, pc))));
        }
        // issue value loads BEFORE the shuffle chain so both HBM exposures overlap
        const float2* vp = (const float2*)(g_vals + kvb);
        float2 vf[NS];
#pragma unroll
        for (int n = 0; n < NS; ++n) vf[n] = vp[n*64 + lane];
        const float2 cki = *(const float2*)&prv_s[r][2*lane];
        const float2 cvi = *(const float2*)&hid_s[r][2*lane];

        // reduce across the 8 chunk-lanes of each slot group (3 hops)
        pk += __shfl_xor(pk, 1); pk += __shfl_xor(pk, 2); pk += __shfl_xor(pk, 4);
        pq += __shfl_xor(pq, 1); pq += __shfl_xor(pq, 2); pq += __shfl_xor(pq, 4);
        pc += __shfl_xor(pc, 1); pc += __shfl_xor(pc, 2); pc += __shfl_xor(pc, 4);
        const float ki   = 1.0f / fmaxf(sqrtf(pk), 1e-6f);
        const float csn  = pq * ki;                  // q_hat . k_hat  (this lane's slot)
        const float simn = pc * ki * ckinv_s[r];     // ck_hat . k_hat
        float cs[NS], sim[NS];
#pragma unroll
        for (int m = 0; m < NS; ++m) {
            cs[m]  = __shfl(csn,  m*8);
            sim[m] = __shfl(simn, m*8);
        }

        // scalar heads (precomputed)
        const float4 hd = *(const float4*)&head_s[r][0];
        const float mix   = sigm(hd.x + bmix);
        const float wsv   = sigm(hd.y + bwr);
        const float pev   = sigm(hd.z + bpe);
        const float mglin = hd.w + bmg;

        // content softmax
        float mC = cs[0];
#pragma unroll
        for (int n = 1; n < NS; ++n) mC = fmaxf(mC, cs[n]);
        float eC[NS], sC = 0.f;
#pragma unroll
        for (int n = 0; n < NS; ++n) { eC[n] = __expf((cs[n]-mC)*4.0f); sC += eC[n]; }
        // persistent softmax
        const float4 st0 = *(const float4*)&str_s[r*NS];
        const float4 st1 = *(const float4*)&str_s[r*NS+4];
        const float4 ag0 = *(const float4*)&age_s[r*NS];
        const float4 ag1 = *(const float4*)&age_s[r*NS+4];
        const float stv[NS] = {st0.x,st0.y,st0.z,st0.w,st1.x,st1.y,st1.z,st1.w};
        const float agv[NS] = {ag0.x,ag0.y,ag0.z,ag0.w,ag1.x,ag1.y,ag1.z,ag1.w};
        float psc[NS]; float mP = -1e30f;
#pragma unroll
        for (int n = 0; n < NS; ++n) {
            psc[n] = fmaf(2.4f, stv[n], 0.6f*(1.0f - agv[n]));
            mP = fmaxf(mP, psc[n]);
        }
        float eP[NS], sP = 0.f;
#pragma unroll
        for (int n = 0; n < NS; ++n) { eP[n] = __expf((psc[n]-mP)*4.0f); sP += eP[n]; }
        const float icS = 1.0f/sC, ipS = 1.0f/sP;

        float2 cr = make_float2(0.f, 0.f), prd = make_float2(0.f, 0.f);
#pragma unroll
        for (int n = 0; n < NS; ++n) {
            float wc = eC[n]*icS, wp = eP[n]*ipS;
            cr.x  = fmaf(wc, vf[n].x, cr.x);  cr.y  = fmaf(wc, vf[n].y, cr.y);
            prd.x = fmaf(wp, vf[n].x, prd.x); prd.y = fmaf(wp, vf[n].y, prd.y);
        }
        float2 mr;
        mr.x = mix*cr.x + (1.0f-mix)*prd.x;
        mr.y = mix*cr.y + (1.0f-mix)*prd.y;
        nt_store2(mr, &((float2*)(o_read + row*BD))[lane]);

        // top-3 of sim (ties -> lowest index, matching lax.top_k).
        // NO runtime-indexed register arrays (rule #20): mask via compares.
        float tv0 = -1e30f; int ti0 = 0;
#pragma unroll
        for (int n = 0; n < NS; ++n) if (sim[n] > tv0) { tv0 = sim[n]; ti0 = n; }
        float tv1 = -1e30f; int ti1 = 0;
#pragma unroll
        for (int n = 0; n < NS; ++n) {
            float v = (n == ti0) ? -1e30f : sim[n];
            if (v > tv1) { tv1 = v; ti1 = n; }
        }
        float tv2 = -1e30f; int ti2 = 0;
#pragma unroll
        for (int n = 0; n < NS; ++n) {
            float v = (n == ti0 || n == ti1) ? -1e30f : sim[n];
            if (v > tv2) { tv2 = v; ti2 = n; }
        }

        // replace argmax (first max)
        float rm = -1e30f; int ri = 0;
#pragma unroll
        for (int n = 0; n < NS; ++n) {
            float rsv = fmaf(1.2f, agv[n], (1.0f - stv[n])) + 0.5f*(1.0f - sim[n]);
            if (rsv > rm) { rm = rsv; ri = n; }
        }

        const float mpref = sigm(mglin + 2.6f*tv0);
        const bool full  = (tv0 > 0.78f) && (mpref >= 0.55f);
        const bool multi = full && (tv1 > 0.68f);
        const bool part  = (!multi) && (tv0 > 0.64f) && (tv1 > 0.52f);
        const float nov  = fminf(fmaxf(1.0f - tv0, 0.0f), 1.0f);

        // target weights as scalars (wave-uniform branch; no target[] array)
        float a0, a1, a2, aR;
        if (multi) {
            float e1 = __expf((tv1 - tv0)*4.0f), e2 = __expf((tv2 - tv0)*4.0f);
            float inv = 1.0f/(1.0f + e1 + e2);
            a0 = inv; a1 = e1*inv; a2 = e2*inv; aR = 0.f;
        } else if (part) {
            float e1 = __expf((tv1 - tv0)*4.0f);
            float inv = 1.0f/(1.0f + e1);
            a0 = inv; a1 = e1*inv; a2 = 0.f; aR = 0.f;
        } else if (full) {
            a0 = 1.f; a1 = 0.f; a2 = 0.f; aR = 0.f;
        } else {
            a0 = 0.f; a1 = 0.f; a2 = 0.f; aR = 1.f;
        }

        const float scl = multi ? fmaf(0.52f, wsv, 0.16f)
                        : part  ? fmaf(0.62f, wsv, 0.18f)
                                : fmaf(0.80f, wsv, 0.20f);
        const bool  mlike = full || part || multi;
        const float km  = mlike ? fmaf(0.24f, pev, 0.28f) : fmaf(0.16f, pev, 0.78f);
        const float vm  = mlike ? fmaf(0.28f, pev, 0.42f) : fmaf(0.12f, pev, 0.82f);
        const float owc = scl * fmaf(0.45f, nov, 0.55f);
        const float bco = 0.45f + 0.35f*pev + 0.45f*nov + 0.25f*wsv;

        const float2* kp2 = (const float2*)(g_keys + kvb);
        float2* okp = (float2*)(o_keys + kvb);
        float2* ovp = (float2*)(o_vals + kvb);
#pragma unroll
        for (int n = 0; n < NS; ++n) {
            const float2 kf2 = kp2[n*64 + lane];   // L1-hot (row read above)
            float tn = ((n==ti0) ? a0 : (n==ti1) ? a1 : (n==ti2) ? a2 : 0.f)
                     + ((n==ri) ? aR : 0.f);
            float ow = tn*owc;
            float a = ow*km, b2 = ow*vm;
            float2 uk, uv;
            uk.x = fmaf(a,  cki.x - kf2.x, kf2.x);
            uk.y = fmaf(a,  cki.y - kf2.y, kf2.y);
            uv.x = fmaf(b2, cvi.x - vf[n].x, vf[n].x);
            uv.y = fmaf(b2, cvi.y - vf[n].y, vf[n].y);
            nt_store2(uk, &okp[n*64 + lane]);
            nt_store2(uv, &ovp[n*64 + lane]);
        }
        if (lane < NS) {
            float tn = ((lane==ti0) ? a0 : (lane==ti1) ? a1 : (lane==ti2) ? a2 : 0.f)
                     + ((lane==ri) ? aR : 0.f);
            float ow = tn*owc;
            float us = fminf(fmaxf(fmaf(str_s[r*NS+lane], 0.99f, ow*bco), 0.f), 1.f);
            float ua = fminf(fmaxf((age_s[r*NS+lane] + 0.02f)*(1.0f - ow), 0.f), 1.f);
            o_str[row*NS + lane] = us;
            o_age[row*NS + lane] = ua;
        }
    }
}

extern "C" void kernel_launch(void* const* d_in, const int* in_sizes, int n_in,
                              void* d_out, int out_size, void* d_ws, size_t ws_size,
                              hipStream_t stream) {
    const float* g_signal = (const float*)d_in[0];
    const float* g_prev   = (const float*)d_in[1];
    const float* g_hidden = (const float*)d_in[2];
    const float* g_keys   = (const float*)d_in[3];
    const float* g_vals   = (const float*)d_in[4];
    const float* g_str    = (const float*)d_in[5];
    const float* g_age    = (const float*)d_in[6];
    const float* w_rq     = (const float*)d_in[7];
    const float* w_mix    = (const float*)d_in[8];
    const float* b_mix    = (const float*)d_in[9];
    const float* w_key    = (const float*)d_in[10];
    const float* b_key    = (const float*)d_in[11];
    const float* w_val    = (const float*)d_in[12];
    const float* b_val    = (const float*)d_in[13];
    const float* w_wr     = (const float*)d_in[14];
    const float* b_wr     = (const float*)d_in[15];
    const float* w_pe     = (const float*)d_in[16];
    const float* b_pe     = (const float*)d_in[17];
    const float* w_mg     = (const float*)d_in[18];
    const float* b_mg     = (const float*)d_in[19];

    const size_t B = (size_t)in_sizes[0] / BD;   // 32768
    float* out   = (float*)d_out;
    float* o_read = out;
    float* o_keys = o_read + B*BD;
    float* o_vals = o_keys + B*NS*BD;
    float* o_str  = o_vals + B*NS*BD;
    float* o_age  = o_str  + B*NS;

    const int blocks = (int)(B / ROWS);
    sbcore_kernel<<<dim3(blocks), dim3(BLOCK), 0, stream>>>(
        g_signal, g_prev, g_hidden, g_keys, g_vals, g_str, g_age,
        w_rq, w_mix, b_mix, w_key, b_key, w_val, b_val,
        w_wr, b_wr, w_pe, b_pe, w_mg, b_mg,
        o_read, o_keys, o_vals, o_str, o_age);
}

// Round 9
// 613.318 us; speedup vs baseline: 1.2032x; 1.2032x over previous
//
#include <hip/hip_runtime.h>
#include <cstddef>

#define BD 128
#define NS 8
#define ROWS 4
#define BLOCK 256

typedef float __attribute__((ext_vector_type(4))) f32x4;
typedef float __attribute__((ext_vector_type(2))) f32x2;

__device__ __forceinline__ float sigm(float x) { return 1.0f / (1.0f + __expf(-x)); }

__device__ __forceinline__ void nt_store2(float2 v, float2* p) {
    f32x2 t; t.x = v.x; t.y = v.y;
    __builtin_nontemporal_store(t, (f32x2*)p);
}

// Phase-1 restructure: thread = (k-group, d-group). 96 float4 weight loads/thread
// (vs 768 scalar), 64 broadcast ds_read_b128 (vs 384). bounds(256,3): VGPR cap
// ~170 -> no spill (R8 lesson: spills at cap 64 cost +300MB traffic, +97us).
__global__ __launch_bounds__(BLOCK, 3)
void sbcore_kernel(
    const float* __restrict__ g_signal, const float* __restrict__ g_prev,
    const float* __restrict__ g_hidden, const float* __restrict__ g_keys,
    const float* __restrict__ g_vals, const float* __restrict__ g_str,
    const float* __restrict__ g_age,
    const float* __restrict__ w_rq, const float* __restrict__ w_mix,
    const float* __restrict__ b_mix, const float* __restrict__ w_key,
    const float* __restrict__ b_key, const float* __restrict__ w_val,
    const float* __restrict__ b_val, const float* __restrict__ w_wr,
    const float* __restrict__ b_wr, const float* __restrict__ w_pe,
    const float* __restrict__ b_pe, const float* __restrict__ w_mg,
    const float* __restrict__ b_mg,
    float* __restrict__ o_read, float* __restrict__ o_keys,
    float* __restrict__ o_vals, float* __restrict__ o_str,
    float* __restrict__ o_age)
{
    // sig/prv/hid staged, then (after k-loop is done) overwritten with q/ck/cv.
    __shared__ __align__(16) float sig_s[ROWS][BD];
    __shared__ __align__(16) float prv_s[ROWS][BD];
    __shared__ __align__(16) float hid_s[ROWS][BD];
    __shared__ __align__(16) f32x4 part_s[4][3][ROWS][32];   // 24 KB k-partials
    __shared__ float str_s[ROWS*NS], age_s[ROWS*NS];
    __shared__ __align__(16) float head_s[ROWS][4];          // pmix,pwr,ppe,pmg

    const int tid = threadIdx.x;
    const int row0 = blockIdx.x * ROWS;

    // ---- phase 0: staging (float4) ----
    if (tid < ROWS*32) {
        int r = tid >> 5, d4 = tid & 31;
        size_t gb = (size_t)(row0 + r) * 32 + d4;   // float4 index
        *(float4*)&sig_s[r][d4*4] = ((const float4*)g_signal)[gb];
        *(float4*)&prv_s[r][d4*4] = ((const float4*)g_prev)[gb];
        *(float4*)&hid_s[r][d4*4] = ((const float4*)g_hidden)[gb];
    }
    if (tid < ROWS*NS) {
        str_s[tid] = g_str[(size_t)row0*NS + tid];
        age_s[tid] = g_age[(size_t)row0*NS + tid];
    }
    __syncthreads();

    // ---- phase 0.5: scalar heads. 16 dots (4 rows x 4 heads) x 16 threads. ----
    {
        const int dotid = tid >> 4;       // 0..15
        const int hr = dotid >> 2;        // row
        const int hh = dotid & 3;         // head
        const int hj = tid & 15;          // 16-dim chunk of K=256
        const float* ws = (hh==0) ? w_mix : (hh==1) ? w_wr : (hh==2) ? w_pe : w_mg;
        const float* xb = (hj < 8) ? &sig_s[hr][0]
                        : (((hh==0) ? &prv_s[hr][0] : &hid_s[hr][0]) - BD);
        float p = 0.f;
#pragma unroll
        for (int q = 0; q < 4; ++q) {
            const int k = hj*16 + q*4;
            const float4 w4 = *(const float4*)&ws[k];
            const float4 x4 = *(const float4*)&xb[k];
            p = fmaf(x4.w, w4.w, fmaf(x4.z, w4.z, fmaf(x4.y, w4.y, fmaf(x4.x, w4.x, p))));
        }
        p += __shfl_xor(p, 1); p += __shfl_xor(p, 2);
        p += __shfl_xor(p, 4); p += __shfl_xor(p, 8);
        if (hj == 0) head_s[hr][hh] = p;
    }

    const int wave = tid >> 6;       // 0..3 (= phase-2 row, = low k-group)
    const int lane = tid & 63;
    const int hi   = lane >> 5;      // 0: k in [wave*32,+32); 1: k in [128+wave*32,+32)
    const int dg   = lane & 31;      // output float4 group: d = dg*4..dg*4+3

    // ---- phase 1: k-split x d-vectorized matvecs ----
    {
        const int kbase = hi ? (BD + wave*32) : (wave*32);
        const f32x4* wq4 = (const f32x4*)w_rq;   // [256][32] float4 view
        const f32x4* wk4 = (const f32x4*)w_key;
        const f32x4* wv4 = (const f32x4*)w_val;
        const int wi0 = kbase*32 + dg;
        const float* x1b = hi ? &prv_s[0][0] : &sig_s[0][0];  // q source
        const float* x2b = hi ? &hid_s[0][0] : &sig_s[0][0];  // k/v source
        const int xo = wave*32;

        f32x4 aq[ROWS], ak[ROWS], av[ROWS];
#pragma unroll
        for (int r = 0; r < ROWS; ++r) { aq[r] = 0.f; ak[r] = 0.f; av[r] = 0.f; }

#pragma unroll 2
        for (int j = 0; j < 8; ++j) {
            const int kj = j*4;
            // q pass (weights live: 16 regs)
            f32x4 w0 = wq4[wi0 + (kj+0)*32], w1 = wq4[wi0 + (kj+1)*32],
                  w2 = wq4[wi0 + (kj+2)*32], w3 = wq4[wi0 + (kj+3)*32];
#pragma unroll
            for (int r = 0; r < ROWS; ++r) {
                const f32x4 x1 = *(const f32x4*)&x1b[r*BD + xo + kj];  // broadcast read
                aq[r] += x1.x*w0; aq[r] += x1.y*w1; aq[r] += x1.z*w2; aq[r] += x1.w*w3;
            }
            // k+v pass (weights live: 32 regs)
            f32x4 k0 = wk4[wi0 + (kj+0)*32], k1 = wk4[wi0 + (kj+1)*32],
                  k2 = wk4[wi0 + (kj+2)*32], k3 = wk4[wi0 + (kj+3)*32];
            f32x4 v0 = wv4[wi0 + (kj+0)*32], v1 = wv4[wi0 + (kj+1)*32],
                  v2 = wv4[wi0 + (kj+2)*32], v3 = wv4[wi0 + (kj+3)*32];
#pragma unroll
            for (int r = 0; r < ROWS; ++r) {
                const f32x4 x2 = *(const f32x4*)&x2b[r*BD + xo + kj];
                ak[r] += x2.x*k0; ak[r] += x2.y*k1; ak[r] += x2.z*k2; ak[r] += x2.w*k3;
                av[r] += x2.x*v0; av[r] += x2.y*v1; av[r] += x2.z*v2; av[r] += x2.w*v3;
            }
        }

        // pair-sum across the two k-halves in this wave (lanes l <-> l+32)
#pragma unroll
        for (int r = 0; r < ROWS; ++r) {
            f32x4 t;
            t.x = __shfl_xor(aq[r].x, 32); t.y = __shfl_xor(aq[r].y, 32);
            t.z = __shfl_xor(aq[r].z, 32); t.w = __shfl_xor(aq[r].w, 32);
            aq[r] += t;
            t.x = __shfl_xor(ak[r].x, 32); t.y = __shfl_xor(ak[r].y, 32);
            t.z = __shfl_xor(ak[r].z, 32); t.w = __shfl_xor(ak[r].w, 32);
            ak[r] += t;
            t.x = __shfl_xor(av[r].x, 32); t.y = __shfl_xor(av[r].y, 32);
            t.z = __shfl_xor(av[r].z, 32); t.w = __shfl_xor(av[r].w, 32);
            av[r] += t;
        }
        if (!hi) {
#pragma unroll
            for (int r = 0; r < ROWS; ++r) {
                part_s[wave][0][r][dg] = aq[r];
                part_s[wave][1][r][dg] = ak[r];
                part_s[wave][2][r][dg] = av[r];
            }
        }
    }
    __syncthreads();

    // ---- final reduce: wave owns row r=wave; lane l owns d = 2l, 2l+1 ----
    const int r = wave;
    float ckinv_reg;
    {
        const int dgf = lane >> 1;            // float4 group
        const int co  = (lane & 1) * 2;       // component offset (0 or 2)
        float2 sq = make_float2(0.f, 0.f), sk = make_float2(0.f, 0.f),
               sv = make_float2(0.f, 0.f);
#pragma unroll
        for (int pw = 0; pw < 4; ++pw) {
            const float* pq = (const float*)&part_s[pw][0][r][dgf];
            const float* pk = (const float*)&part_s[pw][1][r][dgf];
            const float* pv = (const float*)&part_s[pw][2][r][dgf];
            const float2 tq = *(const float2*)&pq[co];
            const float2 tk = *(const float2*)&pk[co];
            const float2 tv = *(const float2*)&pv[co];
            sq.x += tq.x; sq.y += tq.y;
            sk.x += tk.x; sk.y += tk.y;
            sv.x += tv.x; sv.y += tv.y;
        }
        const float2 bk2 = *(const float2*)&b_key[2*lane];
        const float2 bv2 = *(const float2*)&b_val[2*lane];
        const float ckx = tanhf(sk.x + bk2.x), cky = tanhf(sk.y + bk2.y);
        const float cvx = tanhf(sv.x + bv2.x), cvy = tanhf(sv.y + bv2.y);
        float q2 = sq.x*sq.x + sq.y*sq.y;
        float c2 = ckx*ckx + cky*cky;
#pragma unroll
        for (int off = 32; off > 0; off >>= 1) {
            q2 += __shfl_xor(q2, off);
            c2 += __shfl_xor(c2, off);
        }
        const float qinv = 1.0f / fmaxf(sqrtf(q2), 1e-6f);
        ckinv_reg = 1.0f / fmaxf(sqrtf(c2), 1e-6f);
        // overwrite staging rows (k-loop done; each wave touches only its own row)
        *(float2*)&sig_s[r][2*lane] = make_float2(sq.x*qinv, sq.y*qinv);
        *(float2*)&prv_s[r][2*lane] = make_float2(ckx, cky);
        *(float2*)&hid_s[r][2*lane] = make_float2(cvx, cvy);
    }
    __syncthreads();

    // ---- phase 2: wave = row, slot logic (R2-verified body) ----
    const float bmix = b_mix[0], bwr = b_wr[0], bpe = b_pe[0], bmg = b_mg[0];
    const int sj = lane & 7;
    {
        const size_t row = (size_t)row0 + r;
        const size_t kvb = row * (size_t)(NS*BD);

        const float4* kp4  = (const float4*)(g_keys + kvb);
        const float4* qrow = (const float4*)&sig_s[r][0];
        const float4* crow = (const float4*)&prv_s[r][0];
        float pk = 0.f, pq = 0.f, pc = 0.f;
#pragma unroll
        for (int q = 0; q < 4; ++q) {
            const float4 k4 = kp4[4*lane + q];
            const float4 q4 = qrow[sj*4 + q];
            const float4 c4 = crow[sj*4 + q];
            pk = fmaf(k4.w,k4.w, fmaf(k4.z,k4.z, fmaf(k4.y,k4.y, fmaf(k4.x,k4.x, pk))));
            pq = fmaf(q4.w,k4.w, fmaf(q4.z,k4.z, fmaf(q4.y,k4.y, fmaf(q4.x,k4.x, pq))));
            pc = fmaf(c4.w,k4.w, fmaf(c4.z,k4.z, fmaf(c4.y,k4.y, fmaf(c4.x,k4.x, pc))));
        }
        const float2* vp = (const float2*)(g_vals + kvb);
        float2 vf[NS];
#pragma unroll
        for (int n = 0; n < NS; ++n) vf[n] = vp[n*64 + lane];
        const float2 cki = *(const float2*)&prv_s[r][2*lane];
        const float2 cvi = *(const float2*)&hid_s[r][2*lane];

        pk += __shfl_xor(pk, 1); pk += __shfl_xor(pk, 2); pk += __shfl_xor(pk, 4);
        pq += __shfl_xor(pq, 1); pq += __shfl_xor(pq, 2); pq += __shfl_xor(pq, 4);
        pc += __shfl_xor(pc, 1); pc += __shfl_xor(pc, 2); pc += __shfl_xor(pc, 4);
        const float ki   = 1.0f / fmaxf(sqrtf(pk), 1e-6f);
        const float csn  = pq * ki;
        const float simn = pc * ki * ckinv_reg;
        float cs[NS], sim[NS];
#pragma unroll
        for (int m = 0; m < NS; ++m) {
            cs[m]  = __shfl(csn,  m*8);
            sim[m] = __shfl(simn, m*8);
        }

        const float4 hd = *(const float4*)&head_s[r][0];
        const float mix   = sigm(hd.x + bmix);
        const float wsv   = sigm(hd.y + bwr);
        const float pev   = sigm(hd.z + bpe);
        const float mglin = hd.w + bmg;

        float mC = cs[0];
#pragma unroll
        for (int n = 1; n < NS; ++n) mC = fmaxf(mC, cs[n]);
        float eC[NS], sC = 0.f;
#pragma unroll
        for (int n = 0; n < NS; ++n) { eC[n] = __expf((cs[n]-mC)*4.0f); sC += eC[n]; }
        const float4 st0 = *(const float4*)&str_s[r*NS];
        const float4 st1 = *(const float4*)&str_s[r*NS+4];
        const float4 ag0 = *(const float4*)&age_s[r*NS];
        const float4 ag1 = *(const float4*)&age_s[r*NS+4];
        const float stv[NS] = {st0.x,st0.y,st0.z,st0.w,st1.x,st1.y,st1.z,st1.w};
        const float agv[NS] = {ag0.x,ag0.y,ag0.z,ag0.w,ag1.x,ag1.y,ag1.z,ag1.w};
        float psc[NS]; float mP = -1e30f;
#pragma unroll
        for (int n = 0; n < NS; ++n) {
            psc[n] = fmaf(2.4f, stv[n], 0.6f*(1.0f - agv[n]));
            mP = fmaxf(mP, psc[n]);
        }
        float eP[NS], sP = 0.f;
#pragma unroll
        for (int n = 0; n < NS; ++n) { eP[n] = __expf((psc[n]-mP)*4.0f); sP += eP[n]; }
        const float icS = 1.0f/sC, ipS = 1.0f/sP;

        float2 cr = make_float2(0.f, 0.f), prd = make_float2(0.f, 0.f);
#pragma unroll
        for (int n = 0; n < NS; ++n) {
            float wc = eC[n]*icS, wp = eP[n]*ipS;
            cr.x  = fmaf(wc, vf[n].x, cr.x);  cr.y  = fmaf(wc, vf[n].y, cr.y);
            prd.x = fmaf(wp, vf[n].x, prd.x); prd.y = fmaf(wp, vf[n].y, prd.y);
        }
        float2 mr;
        mr.x = mix*cr.x + (1.0f-mix)*prd.x;
        mr.y = mix*cr.y + (1.0f-mix)*prd.y;
        nt_store2(mr, &((float2*)(o_read + row*BD))[lane]);

        // top-3 (ties -> lowest index), no runtime-indexed register arrays
        float tv0 = -1e30f; int ti0 = 0;
#pragma unroll
        for (int n = 0; n < NS; ++n) if (sim[n] > tv0) { tv0 = sim[n]; ti0 = n; }
        float tv1 = -1e30f; int ti1 = 0;
#pragma unroll
        for (int n = 0; n < NS; ++n) {
            float v = (n == ti0) ? -1e30f : sim[n];
            if (v > tv1) { tv1 = v; ti1 = n; }
        }
        float tv2 = -1e30f; int ti2 = 0;
#pragma unroll
        for (int n = 0; n < NS; ++n) {
            float v = (n == ti0 || n == ti1) ? -1e30f : sim[n];
            if (v > tv2) { tv2 = v; ti2 = n; }
        }

        float rm = -1e30f; int ri = 0;
#pragma unroll
        for (int n = 0; n < NS; ++n) {
            float rsv = fmaf(1.2f, agv[n], (1.0f - stv[n])) + 0.5f*(1.0f - sim[n]);
            if (rsv > rm) { rm = rsv; ri = n; }
        }

        const float mpref = sigm(mglin + 2.6f*tv0);
        const bool full  = (tv0 > 0.78f) && (mpref >= 0.55f);
        const bool multi = full && (tv1 > 0.68f);
        const bool part  = (!multi) && (tv0 > 0.64f) && (tv1 > 0.52f);
        const float nov  = fminf(fmaxf(1.0f - tv0, 0.0f), 1.0f);

        float a0, a1, a2, aR;
        if (multi) {
            float e1 = __expf((tv1 - tv0)*4.0f), e2 = __expf((tv2 - tv0)*4.0f);
            float inv = 1.0f/(1.0f + e1 + e2);
            a0 = inv; a1 = e1*inv; a2 = e2*inv; aR = 0.f;
        } else if (part) {
            float e1 = __expf((tv1 - tv0)*4.0f);
            float inv = 1.0f/(1.0f + e1);
            a0 = inv; a1 = e1*inv; a2 = 0.f; aR = 0.f;
        } else if (full) {
            a0 = 1.f; a1 = 0.f; a2 = 0.f; aR = 0.f;
        } else {
            a0 = 0.f; a1 = 0.f; a2 = 0.f; aR = 1.f;
        }

        const float scl = multi ? fmaf(0.52f, wsv, 0.16f)
                        : part  ? fmaf(0.62f, wsv, 0.18f)
                                : fmaf(0.80f, wsv, 0.20f);
        const bool  mlike = full || part || multi;
        const float km  = mlike ? fmaf(0.24f, pev, 0.28f) : fmaf(0.16f, pev, 0.78f);
        const float vm  = mlike ? fmaf(0.28f, pev, 0.42f) : fmaf(0.12f, pev, 0.82f);
        const float owc = scl * fmaf(0.45f, nov, 0.55f);
        const float bco = 0.45f + 0.35f*pev + 0.45f*nov + 0.25f*wsv;

        const float2* kp2 = (const float2*)(g_keys + kvb);
        float2* okp = (float2*)(o_keys + kvb);
        float2* ovp = (float2*)(o_vals + kvb);
#pragma unroll
        for (int n = 0; n < NS; ++n) {
            const float2 kf2 = kp2[n*64 + lane];
            float tn = ((n==ti0) ? a0 : (n==ti1) ? a1 : (n==ti2) ? a2 : 0.f)
                     + ((n==ri) ? aR : 0.f);
            float ow = tn*owc;
            float a = ow*km, b2 = ow*vm;
            float2 uk, uv;
            uk.x = fmaf(a,  cki.x - kf2.x, kf2.x);
            uk.y = fmaf(a,  cki.y - kf2.y, kf2.y);
            uv.x = fmaf(b2, cvi.x - vf[n].x, vf[n].x);
            uv.y = fmaf(b2, cvi.y - vf[n].y, vf[n].y);
            nt_store2(uk, &okp[n*64 + lane]);
            nt_store2(uv, &ovp[n*64 + lane]);
        }
        if (lane < NS) {
            float tn = ((lane==ti0) ? a0 : (lane==ti1) ? a1 : (lane==ti2) ? a2 : 0.f)
                     + ((lane==ri) ? aR : 0.f);
            float ow = tn*owc;
            float us = fminf(fmaxf(fmaf(str_s[r*NS+lane], 0.99f, ow*bco), 0.f), 1.f);
            float ua = fminf(fmaxf((age_s[r*NS+lane] + 0.02f)*(1.0f - ow), 0.f), 1.f);
            o_str[row*NS + lane] = us;
            o_age[row*NS + lane] = ua;
        }
    }
}

extern "C" void kernel_launch(void* const* d_in, const int* in_sizes, int n_in,
                              void* d_out, int out_size, void* d_ws, size_t ws_size,
                              hipStream_t stream) {
    const float* g_signal = (const float*)d_in[0];
    const float* g_prev   = (const float*)d_in[1];
    const float* g_hidden = (const float*)d_in[2];
    const float* g_keys   = (const float*)d_in[3];
    const float* g_vals   = (const float*)d_in[4];
    const float* g_str    = (const float*)d_in[5];
    const float* g_age    = (const float*)d_in[6];
    const float* w_rq     = (const float*)d_in[7];
    const float* w_mix    = (const float*)d_in[8];
    const float* b_mix    = (const float*)d_in[9];
    const float* w_key    = (const float*)d_in[10];
    const float* b_key    = (const float*)d_in[11];
    const float* w_val    = (const float*)d_in[12];
    const float* b_val    = (const float*)d_in[13];
    const float* w_wr     = (const float*)d_in[14];
    const float* b_wr     = (const float*)d_in[15];
    const float* w_pe     = (const float*)d_in[16];
    const float* b_pe     = (const float*)d_in[17];
    const float* w_mg     = (const float*)d_in[18];
    const float* b_mg     = (const float*)d_in[19];

    const size_t B = (size_t)in_sizes[0] / BD;   // 32768
    float* out   = (float*)d_out;
    float* o_read = out;
    float* o_keys = o_read + B*BD;
    float* o_vals = o_keys + B*NS*BD;
    float* o_str  = o_vals + B*NS*BD;
    float* o_age  = o_str  + B*NS;

    const int blocks = (int)(B / ROWS);          // 8192
    sbcore_kernel<<<dim3(blocks), dim3(BLOCK), 0, stream>>>(
        g_signal, g_prev, g_hidden, g_keys, g_vals, g_str, g_age,
        w_rq, w_mix, b_mix, w_key, b_key, w_val, b_val,
        w_wr, b_wr, w_pe, b_pe, w_mg, b_mg,
        o_read, o_keys, o_vals, o_str, o_age);
}